// Round 5
// baseline (852.105 us; speedup 1.0000x reference)
//
#include <hip/hip_runtime.h>
#include <cstdint>
#include <cstddef>

// ---------------------------------------------------------------------------
// AlphaNet: features -> BN -> conv(1x3,16) -> relu -> fc1(43200->512) -> relu
//          -> fc2(512->128) -> sigmoid -> fc3(128->1)
// fc1 = f16 MFMA GEMM (A scaled 2^-8), split-K=25, atomic fp32 reduce.
// R5: A in plain row-major [mt][it64][128][64] (line-complete stage_a writes,
//     64B-segment gemm reads); W in MFMA fragment order (coalesced 16B/lane).
//     Barrier-free LDS-free GEMM; grid 1600 blocks (6.25/CU) for TLP latency
//     hiding.
// ---------------------------------------------------------------------------

typedef _Float16 f16;
typedef f16 f16x8 __attribute__((ext_vector_type(8)));
typedef float f32x4 __attribute__((ext_vector_type(4)));

#define CHUNK    2048              // samples per pipeline pass (2 passes)
#define K_FC1    43200             // 16*270*10
#define IT_TOT   675               // K_FC1 / 64
#define SPLITK   25
#define IT_BLK   27                // 675 / 25
#define MT_CHUNK 16                // 2048 / 128
#define TILE_ELEMS 8192            // 128*64 f16 per (tile,it) block

__device__ __forceinline__ float fillv(float x) { return isfinite(x) ? x : 0.0f; }

// ---------------------------------------------------------------------------
// Kernel 1: fc1_w fp32 -> f16, retiled to MFMA fragment order:
// unit layout per (nt,it): [g(8)][h(2)][quad(4)][m16(16)] x 16B,
// lane = quad*16+m16 holds W[g*16+m16][h*32+quad*8+j], j=0..7.
// One block per (nt,it) = 2700 blocks.
// ---------------------------------------------------------------------------
__global__ __launch_bounds__(256) void retile_w(const float* __restrict__ w,
                                                f16* __restrict__ Wt) {
    const int bid = blockIdx.x;               // nt*675 + it
    const int nt = bid / 675, it = bid % 675;
    const int t = threadIdx.x;
    f16* dst = Wt + (size_t)bid * TILE_ELEMS;
    #pragma unroll
    for (int j = 0; j < 4; ++j) {
        int t2 = t + 256 * j;                 // 0..1023 16B units
        int r = t2 >> 3, u = t2 & 7;          // row, k-octet
        int h = u >> 2, q = u & 3;
        int g = r >> 4, m16 = r & 15;
        const float* s = w + (size_t)(nt * 128 + r) * K_FC1 + it * 64 + u * 8;
        float4 a = *(const float4*)s;
        float4 b = *(const float4*)(s + 4);
        f16x8 o = { (f16)a.x, (f16)a.y, (f16)a.z, (f16)a.w,
                    (f16)b.x, (f16)b.y, (f16)b.z, (f16)b.w };
        *(f16x8*)(dst + g * 1024 + h * 512 + q * 128 + m16 * 8) = o;
    }
}

// ---------------------------------------------------------------------------
// Kernel 2: per-sample features + BN + conv + relu -> A16 row-major tiled
// (scaled 2^-8). A layout: [mt(16)][it(675)][row(128)][64] f16.
// One block per sample, 256 threads; writes are contiguous 128B per (it).
// Feature rows: corr 0-104 | cov 105-209 | std 210-224 | zs 225-239
//               | ret 240-254 | dl 255-269 ; 12 windows each.
// ---------------------------------------------------------------------------
__global__ __launch_bounds__(256) void stage_a(
    const float* __restrict__ data, const float* __restrict__ bn_g,
    const float* __restrict__ bn_b, const float* __restrict__ bn_m,
    const float* __restrict__ bn_v, const float* __restrict__ conv_w,
    const float* __restrict__ conv_b, f16* __restrict__ A16, int n0)
{
    __shared__ float raw[1800];        // raw window data, becomes spread
    __shared__ float feat[270 * 12];
    __shared__ float cw[48];
    __shared__ float cb[16];
    __shared__ int   pi[105], pj[105];

    const int t = threadIdx.x;
    const int n = n0 + blockIdx.x;
    const float4* src4 = (const float4*)(data + (size_t)n * 1800);
    for (int i = t; i < 450; i += 256) ((float4*)raw)[i] = src4[i];
    if (t < 48)  cw[t] = conv_w[t];
    if (t < 16)  cb[t] = conv_b[t];
    if (t < 105) {                               // triu_indices(15, k=1) order
        int i = 0, rem = t;
        while (rem >= 14 - i) { rem -= 14 - i; ++i; }
        pi[t] = i; pj[t] = i + 1 + rem;
    }
    __syncthreads();

    // per-(f,w) stats; overwrite raw with spread
    if (t < 180) {
        int f = t / 12, w = t % 12;
        int base = f * 120 + w * 10;
        float x[10];
        #pragma unroll
        for (int s = 0; s < 10; ++s) x[s] = raw[base + s];
        float sum = 0.f;
        #pragma unroll
        for (int s = 0; s < 10; ++s) sum += x[s];
        float mean = sum * 0.1f;
        float ret = x[9] / x[0] - 1.0f;
        float dl = 0.f;
        #pragma unroll
        for (int s = 0; s < 10; ++s) dl += x[s] * ((float)(s + 1) * (1.0f / 55.0f));
        float var = 0.f;
        #pragma unroll
        for (int s = 0; s < 10; ++s) { float d = x[s] - mean; raw[base + s] = d; var += d * d; }
        var *= (1.0f / 9.0f);                    // unbiased
        float sd = sqrtf(var);
        feat[(210 + f) * 12 + w] = fillv(sd);
        feat[(225 + f) * 12 + w] = fillv(mean / sd);
        feat[(240 + f) * 12 + w] = fillv(ret);
        feat[(255 + f) * 12 + w] = fillv(dl);
    }
    __syncthreads();

    // pairwise cov / corr
    for (int q = t; q < 1260; q += 256) {
        int p = q / 12, w = q % 12;
        int i = pi[p], j = pj[p];
        int bi = i * 120 + w * 10, bj = j * 120 + w * 10;
        float cv = 0.f;
        #pragma unroll
        for (int s = 0; s < 10; ++s) cv += raw[bi + s] * raw[bj + s];
        cv *= (1.0f / 9.0f);
        float si = feat[(210 + i) * 12 + w], sj = feat[(210 + j) * 12 + w];
        feat[p * 12 + w]         = fillv(cv / (si * sj) * 0.9f);  // *(S-1)/S
        feat[(105 + p) * 12 + w] = fillv(cv);
    }
    __syncthreads();

    // BatchNorm (eval, C=1 scalar)
    float a  = bn_g[0] * rsqrtf(bn_v[0] + 1e-5f);
    float bb = bn_b[0] - bn_m[0] * a;
    for (int i = t; i < 3240; i += 256) feat[i] = feat[i] * a + bb;
    __syncthreads();

    // conv(1x3) + bias + relu -> scale 2^-8 -> clamp -> f16 -> row-major tiled
    const int s_idx = blockIdx.x;                // sample within chunk
    const int mt = s_idx >> 7, r = s_idx & 127;
    f16* base = A16 + (size_t)mt * IT_TOT * TILE_ELEMS + (size_t)r * 64;
    for (int v = t; v < K_FC1 / 8; v += 256) {   // 5400 16B units
        int idx0 = v * 8;
        f16x8 ov;
        #pragma unroll
        for (int e = 0; e < 8; ++e) {
            int idx = idx0 + e;
            int oc = idx / 2700;
            int rem = idx - oc * 2700;
            int h = rem / 10;
            int wo = rem - h * 10;
            const float* fr = feat + h * 12 + wo;
            float y = cb[oc] + cw[oc * 3] * fr[0] + cw[oc * 3 + 1] * fr[1] + cw[oc * 3 + 2] * fr[2];
            y = y > 0.f ? y : 0.f;
            y *= 0.00390625f;                    // 2^-8 (exact)
            y = y < 65000.f ? y : 65000.f;       // fp16-overflow backstop
            ov[e] = (f16)y;
        }
        int it = v >> 3, u = v & 7;
        *(f16x8*)(base + (size_t)it * TILE_ELEMS + u * 8) = ov;
    }
}

// ---------------------------------------------------------------------------
// Kernel 3: fc1 GEMM  Ysum[CHUNK,512] (+)= A * W^T (f16 MFMA)
// Barrier-free, LDS-free. A row-major (16x64B line-complete segments/load),
// W fragment-order (16B/lane coalesced). 128x128 tile, BK=64, split-K=25
// -> 1600 blocks (6.25/CU) for TLP latency hiding.
// XCD swizzle: xcd=bid&7 pins mt-pair per XCD; nt fastest.
// ---------------------------------------------------------------------------
__global__ __launch_bounds__(256, 2) void gemm_fc1(const f16* __restrict__ A,
                                                   const f16* __restrict__ W,
                                                   float* __restrict__ Ysum)
{
    const int bid = blockIdx.x;                   // 1600 blocks
    const int xcd = bid & 7, slot = bid >> 3;     // slot 0..199
    const int nt = slot & 3;
    const int m2 = (slot >> 2) & 1;
    const int sk = slot >> 3;                     // 0..24
    const int mt = xcd * 2 + m2;

    const int tid = threadIdx.x;
    const int wave = tid >> 6, lane = tid & 63;
    const int quad = lane >> 4, m16 = lane & 15;
    const int wm = (wave & 1) << 6, wn = (wave >> 1) << 6;
    const int gb = wn >> 4;                       // 0 or 4 (B fragment group)

    // A: row-major; per-lane base = row (wm+m16), k-octet quad
    const f16* Ab = A + (size_t)(mt * IT_TOT + sk * IT_BLK) * TILE_ELEMS
                    + (size_t)(wm + m16) * 64 + quad * 8;
    // W: fragment order; per-lane base = lane*8
    const f16* Bb = W + (size_t)(nt * IT_TOT + sk * IT_BLK) * TILE_ELEMS
                    + lane * 8;

    f16x8 a[2][2][4], b[2][2][4];                 // [buf][h][i]
    f32x4 acc[4][4] = {};

#define LOADF(B, IT) do {                                                     \
    const f16* Ap = Ab + (size_t)(IT) * TILE_ELEMS;                           \
    const f16* Bp = Bb + (size_t)(IT) * TILE_ELEMS;                           \
    _Pragma("unroll") for (int h_ = 0; h_ < 2; ++h_)                          \
    _Pragma("unroll") for (int i_ = 0; i_ < 4; ++i_) {                        \
        a[B][h_][i_] = *(const f16x8*)(Ap + i_ * (16 * 64) + h_ * 32);        \
        b[B][h_][i_] = *(const f16x8*)(Bp + ((gb + i_) * 2 + h_) * 512);      \
    } } while (0)

#define MFMAF(B) do {                                                         \
    _Pragma("unroll") for (int h_ = 0; h_ < 2; ++h_)                          \
    _Pragma("unroll") for (int i_ = 0; i_ < 4; ++i_)                          \
    _Pragma("unroll") for (int j_ = 0; j_ < 4; ++j_)                          \
        acc[i_][j_] = __builtin_amdgcn_mfma_f32_16x16x32_f16(                 \
            a[B][h_][i_], b[B][h_][j_], acc[i_][j_], 0, 0, 0);                \
    } while (0)

    LOADF(0, 0);
    int it = 1;
    #pragma unroll 1
    for (int k2 = 0; k2 < (IT_BLK - 1) / 2; ++k2) {   // 13 double-steps
        LOADF(1, it);
        MFMAF(0);
        LOADF(0, it + 1);
        MFMAF(1);
        it += 2;
    }
    MFMAF(0);                                     // it = 26 (in buf0)

#undef LOADF
#undef MFMAF

    // C/D layout: col = lane&15, row = quad*4 + reg. Atomic split-K reduce.
    float* Yb = Ysum + (size_t)(mt * 128) * 512 + nt * 128;
    #pragma unroll
    for (int i = 0; i < 4; ++i)
        #pragma unroll
        for (int j = 0; j < 4; ++j)
            #pragma unroll
            for (int r = 0; r < 4; ++r) {
                int row = wm + i * 16 + quad * 4 + r;
                int col = wn + j * 16 + m16;
                unsafeAtomicAdd(&Yb[(size_t)row * 512 + col], acc[i][j][r]);
            }
}

// ---------------------------------------------------------------------------
// Kernel 4: head = (relu(sum*256+b1)) -> fc2 + sigmoid -> fc3
// 8 samples/block, 128 threads -> 256 blocks per chunk.
// ---------------------------------------------------------------------------
__global__ __launch_bounds__(128) void head_fc23(const float* __restrict__ y1s,
                                                 const float* __restrict__ b1,
                                                 const float* __restrict__ w2,
                                                 const float* __restrict__ b2,
                                                 const float* __restrict__ w3,
                                                 const float* __restrict__ b3,
                                                 float* __restrict__ out, int n0)
{
    __shared__ float Ys[8 * 512];    // 16 KB
    __shared__ float Y2[8 * 128];    // 4 KB
    const int t = threadIdx.x;
    const float4* yb = (const float4*)(y1s + (size_t)blockIdx.x * 8 * 512);
    const float4* b1v = (const float4*)b1;
    for (int i = t; i < 8 * 128; i += 128) {
        float4 s = yb[i];
        float4 bv = b1v[i & 127];
        float4 y;
        y.x = fmaxf(fmaf(s.x, 256.f, bv.x), 0.f);
        y.y = fmaxf(fmaf(s.y, 256.f, bv.y), 0.f);
        y.z = fmaxf(fmaf(s.z, 256.f, bv.z), 0.f);
        y.w = fmaxf(fmaf(s.w, 256.f, bv.w), 0.f);
        ((float4*)Ys)[i] = y;
    }
    __syncthreads();

    float acc[8];
    float bk = b2[t];
    #pragma unroll
    for (int s = 0; s < 8; ++s) acc[s] = bk;
    const float4* wr = (const float4*)(w2 + (size_t)t * 512);
    for (int jc = 0; jc < 128; ++jc) {
        float4 w4 = wr[jc];
        #pragma unroll
        for (int s = 0; s < 8; ++s) {
            float4 y4 = *(const float4*)(Ys + s * 512 + jc * 4);
            acc[s] += w4.x * y4.x + w4.y * y4.y + w4.z * y4.z + w4.w * y4.w;
        }
    }
    #pragma unroll
    for (int s = 0; s < 8; ++s) Y2[s * 128 + t] = 1.0f / (1.0f + expf(-acc[s]));
    __syncthreads();

    if (t < 8) {
        float sm = b3[0];
        #pragma unroll 4
        for (int k = 0; k < 128; ++k) sm += Y2[t * 128 + k] * w3[k];
        out[n0 + blockIdx.x * 8 + t] = sm;
    }
}

// ---------------------------------------------------------------------------
extern "C" void kernel_launch(void* const* d_in, const int* in_sizes, int n_in,
                              void* d_out, int out_size, void* d_ws, size_t ws_size,
                              hipStream_t stream)
{
    const float* data = (const float*)d_in[0];
    const float* bn_g = (const float*)d_in[1];
    const float* bn_b = (const float*)d_in[2];
    const float* bn_m = (const float*)d_in[3];
    const float* bn_v = (const float*)d_in[4];
    const float* cw   = (const float*)d_in[5];
    const float* cb   = (const float*)d_in[6];
    const float* fc1w = (const float*)d_in[7];
    const float* fc1b = (const float*)d_in[8];
    const float* fc2w = (const float*)d_in[9];
    const float* fc2b = (const float*)d_in[10];
    const float* fc3w = (const float*)d_in[11];
    const float* fc3b = (const float*)d_in[12];
    float* out = (float*)d_out;

    // workspace layout (total ~225.6 MB, known-safe)
    const size_t A16_BYTES = (size_t)CHUNK * K_FC1 * 2;       // 176,947,200
    const size_t W16_BYTES = (size_t)512 * K_FC1 * 2;         //  44,236,800
    const size_t Y1_BYTES  = (size_t)CHUNK * 512 * 4;         //   4,194,304
    if (ws_size < A16_BYTES + W16_BYTES + Y1_BYTES) return;

    char* ws = (char*)d_ws;
    f16*   A16 = (f16*)ws;
    f16*   W16 = (f16*)(ws + A16_BYTES);
    float* y1s = (float*)(ws + A16_BYTES + W16_BYTES);

    retile_w<<<4 * IT_TOT, 256, 0, stream>>>(fc1w, W16);

    for (int c = 0; c < 2; ++c) {
        int n0 = c * CHUNK;
        hipMemsetAsync(y1s, 0, Y1_BYTES, stream);
        stage_a<<<CHUNK, 256, 0, stream>>>(data, bn_g, bn_b, bn_m, bn_v, cw, cb, A16, n0);
        gemm_fc1<<<8 * 200, 256, 0, stream>>>(A16, W16, y1s);
        head_fc23<<<CHUNK / 8, 128, 0, stream>>>(y1s, fc1b, fc2w, fc2b, fc3w, fc3b, out, n0);
    }
}

// Round 6
// 742.731 us; speedup vs baseline: 1.1473x; 1.1473x over previous
//
#include <hip/hip_runtime.h>
#include <cstdint>
#include <cstddef>

// ---------------------------------------------------------------------------
// AlphaNet: features -> BN -> conv(1x3,16) -> relu -> fc1(43200->512) -> relu
//          -> fc2(512->128) -> sigmoid -> fc3(128->1)
// fc1 = f16 MFMA GEMM (A scaled 2^-8), split-K=27, atomic fp32 reduce.
// R6: 4-deep LDS ring pipeline, raw s_barrier + manual s_waitcnt vmcnt(8)
//     (never vmcnt(0) in steady state) -> global_load_lds stays ~3 iters in
//     flight, hiding HBM latency. BK=32 tiles [it][128][32] with (u+(r>>1))&3
//     unit swizzle baked into A and W global layouts (conflict-free LDS reads,
//     contiguous 1KB staging insts, 64B-contiguous stage_a writes).
// ---------------------------------------------------------------------------

typedef _Float16 f16;
typedef f16 f16x8 __attribute__((ext_vector_type(8)));
typedef float f32x4 __attribute__((ext_vector_type(4)));

#define CHUNK    2048              // samples per pipeline pass (2 passes)
#define K_FC1    43200             // 16*270*10
#define IT_TOT   1350              // K_FC1 / 32
#define SPLITK   27
#define IT_BLK   50                // 1350 / 27
#define MT_CHUNK 16                // 2048 / 128
#define TILE32   4096              // 128*32 f16 per (tile,it) block (8KB)

__device__ __forceinline__ float fillv(float x) { return isfinite(x) ? x : 0.0f; }

// ---------------------------------------------------------------------------
// Kernel 1: fc1_w fp32 -> f16, retiled to [nt(4)][it(1350)][128][32] with
// 16B-unit swizzle: unit u of row r stored at position (u + (r>>1)) & 3.
// One block per (nt,it) = 5400 blocks, 512 units each.
// ---------------------------------------------------------------------------
__global__ __launch_bounds__(256) void retile_w(const float* __restrict__ w,
                                                f16* __restrict__ Wt) {
    const int bid = blockIdx.x;               // nt*1350 + it
    const int nt = bid / IT_TOT, it = bid % IT_TOT;
    const int t = threadIdx.x;
    f16* dst = Wt + (size_t)bid * TILE32;
    #pragma unroll
    for (int j = 0; j < 2; ++j) {
        int t2 = t + 256 * j;                 // 0..511 16B units
        int r = t2 >> 2, u = t2 & 3;          // row, k-octet
        const float* s = w + (size_t)(nt * 128 + r) * K_FC1 + it * 32 + u * 8;
        float4 a = *(const float4*)s;
        float4 b = *(const float4*)(s + 4);
        f16x8 o = { (f16)a.x, (f16)a.y, (f16)a.z, (f16)a.w,
                    (f16)b.x, (f16)b.y, (f16)b.z, (f16)b.w };
        int p = (u + (r >> 1)) & 3;
        *(f16x8*)(dst + (size_t)r * 32 + p * 8) = o;
    }
}

// ---------------------------------------------------------------------------
// Kernel 2: per-sample features + BN + conv + relu -> A16 tiled+swizzled
// (scaled 2^-8). A layout: [mt(16)][it(1350)][128][32] f16, same swizzle.
// One block per sample; per (it) the sample writes one contiguous 64B run.
// ---------------------------------------------------------------------------
__global__ __launch_bounds__(256) void stage_a(
    const float* __restrict__ data, const float* __restrict__ bn_g,
    const float* __restrict__ bn_b, const float* __restrict__ bn_m,
    const float* __restrict__ bn_v, const float* __restrict__ conv_w,
    const float* __restrict__ conv_b, f16* __restrict__ A16, int n0)
{
    __shared__ float raw[1800];        // raw window data, becomes spread
    __shared__ float feat[270 * 12];
    __shared__ float cw[48];
    __shared__ float cb[16];
    __shared__ int   pi[105], pj[105];

    const int t = threadIdx.x;
    const int n = n0 + blockIdx.x;
    const float4* src4 = (const float4*)(data + (size_t)n * 1800);
    for (int i = t; i < 450; i += 256) ((float4*)raw)[i] = src4[i];
    if (t < 48)  cw[t] = conv_w[t];
    if (t < 16)  cb[t] = conv_b[t];
    if (t < 105) {                               // triu_indices(15, k=1) order
        int i = 0, rem = t;
        while (rem >= 14 - i) { rem -= 14 - i; ++i; }
        pi[t] = i; pj[t] = i + 1 + rem;
    }
    __syncthreads();

    // per-(f,w) stats; overwrite raw with spread
    if (t < 180) {
        int f = t / 12, w = t % 12;
        int base = f * 120 + w * 10;
        float x[10];
        #pragma unroll
        for (int s = 0; s < 10; ++s) x[s] = raw[base + s];
        float sum = 0.f;
        #pragma unroll
        for (int s = 0; s < 10; ++s) sum += x[s];
        float mean = sum * 0.1f;
        float ret = x[9] / x[0] - 1.0f;
        float dl = 0.f;
        #pragma unroll
        for (int s = 0; s < 10; ++s) dl += x[s] * ((float)(s + 1) * (1.0f / 55.0f));
        float var = 0.f;
        #pragma unroll
        for (int s = 0; s < 10; ++s) { float d = x[s] - mean; raw[base + s] = d; var += d * d; }
        var *= (1.0f / 9.0f);                    // unbiased
        float sd = sqrtf(var);
        feat[(210 + f) * 12 + w] = fillv(sd);
        feat[(225 + f) * 12 + w] = fillv(mean / sd);
        feat[(240 + f) * 12 + w] = fillv(ret);
        feat[(255 + f) * 12 + w] = fillv(dl);
    }
    __syncthreads();

    // pairwise cov / corr
    for (int q = t; q < 1260; q += 256) {
        int p = q / 12, w = q % 12;
        int i = pi[p], j = pj[p];
        int bi = i * 120 + w * 10, bj = j * 120 + w * 10;
        float cv = 0.f;
        #pragma unroll
        for (int s = 0; s < 10; ++s) cv += raw[bi + s] * raw[bj + s];
        cv *= (1.0f / 9.0f);
        float si = feat[(210 + i) * 12 + w], sj = feat[(210 + j) * 12 + w];
        feat[p * 12 + w]         = fillv(cv / (si * sj) * 0.9f);  // *(S-1)/S
        feat[(105 + p) * 12 + w] = fillv(cv);
    }
    __syncthreads();

    // BatchNorm (eval, C=1 scalar)
    float a  = bn_g[0] * rsqrtf(bn_v[0] + 1e-5f);
    float bb = bn_b[0] - bn_m[0] * a;
    for (int i = t; i < 3240; i += 256) feat[i] = feat[i] * a + bb;
    __syncthreads();

    // conv(1x3) + bias + relu -> scale 2^-8 -> clamp -> f16 -> tiled+swizzled
    const int s_idx = blockIdx.x;                // sample within chunk
    const int mt = s_idx >> 7, r = s_idx & 127;
    const int rsw = (r >> 1) & 3;
    f16* base = A16 + (size_t)mt * IT_TOT * TILE32 + (size_t)r * 32;
    for (int v = t; v < K_FC1 / 8; v += 256) {   // 5400 16B units
        int idx0 = v * 8;
        f16x8 ov;
        #pragma unroll
        for (int e = 0; e < 8; ++e) {
            int idx = idx0 + e;
            int oc = idx / 2700;
            int rem = idx - oc * 2700;
            int h = rem / 10;
            int wo = rem - h * 10;
            const float* fr = feat + h * 12 + wo;
            float y = cb[oc] + cw[oc * 3] * fr[0] + cw[oc * 3 + 1] * fr[1] + cw[oc * 3 + 2] * fr[2];
            y = y > 0.f ? y : 0.f;
            y *= 0.00390625f;                    // 2^-8 (exact)
            y = y < 65000.f ? y : 65000.f;       // fp16-overflow backstop
            ov[e] = (f16)y;
        }
        int it = v >> 2, u = v & 3;
        int p = (u + rsw) & 3;
        *(f16x8*)(base + (size_t)it * TILE32 + p * 8) = ov;
    }
}

// ---------------------------------------------------------------------------
// Kernel 3: fc1 GEMM  Ysum[CHUNK,512] (+)= A * W^T (f16 MFMA)
// 4-deep LDS ring, raw s_barrier + manual vmcnt (no vmcnt(0) drain in steady
// state). 128x128 tile, BK=32, split-K=27 -> 1728 blocks (2 blocks/CU via
// 64KB LDS). XCD swizzle: xcd=bid&7 -> nt=xcd>>1, mt fastest (W L2-hot).
// ---------------------------------------------------------------------------
__global__ __launch_bounds__(256, 2) void gemm_fc1(const f16* __restrict__ A,
                                                   const f16* __restrict__ W,
                                                   float* __restrict__ Ysum)
{
    __shared__ f16 As[4][TILE32];   // 4 x 8KB
    __shared__ f16 Bs[4][TILE32];   // 4 x 8KB

    const int bid = blockIdx.x;
    const int xcd = bid & 7, slot = bid >> 3;     // 216 slots per XCD
    const int nt = xcd >> 1;
    const int idx = slot + (xcd & 1) * 216;       // 0..431 -> (mt, sk)
    const int mt = idx & 15, sk = idx >> 4;       // sk 0..26

    const int tid = threadIdx.x;
    const int wave = tid >> 6, lane = tid & 63;
    const int quad = lane >> 4, m16 = lane & 15;
    const int wm = (wave & 1) << 6, wn = (wave >> 1) << 6;

    const f16* Ab = A + (size_t)(mt * IT_TOT + sk * IT_BLK) * TILE32;
    const f16* Bb = W + (size_t)(nt * IT_TOT + sk * IT_BLK) * TILE32;

    f32x4 acc[4][4] = {};

    // fire one ring stage: this wave's 4 x 1KB contiguous global_load_lds
#define FIRE(ST, IT) do {                                                     \
    const f16* At_ = Ab + (size_t)(IT) * TILE32;                              \
    const f16* Bt_ = Bb + (size_t)(IT) * TILE32;                              \
    _Pragma("unroll") for (int c_ = 0; c_ < 2; ++c_) {                        \
        int n_ = wave + c_ * 4;                                               \
        __builtin_amdgcn_global_load_lds(                                     \
            (const __attribute__((address_space(1))) void*)(At_ + n_ * 512 + lane * 8), \
            (__attribute__((address_space(3))) void*)(&As[ST][n_ * 512]),     \
            16, 0, 0);                                                        \
        __builtin_amdgcn_global_load_lds(                                     \
            (const __attribute__((address_space(1))) void*)(Bt_ + n_ * 512 + lane * 8), \
            (__attribute__((address_space(3))) void*)(&Bs[ST][n_ * 512]),     \
            16, 0, 0);                                                        \
    } } while (0)

#define CONSUME(ST) do {                                                      \
    f16x8 af_[4], bf_[4];                                                     \
    _Pragma("unroll") for (int i_ = 0; i_ < 4; ++i_) {                        \
        int ra_ = wm + i_ * 16 + m16;                                         \
        int pa_ = (quad + (ra_ >> 1)) & 3;                                    \
        af_[i_] = *(const f16x8*)(&As[ST][ra_ * 32 + pa_ * 8]);               \
        int rb_ = wn + i_ * 16 + m16;                                         \
        int pb_ = (quad + (rb_ >> 1)) & 3;                                    \
        bf_[i_] = *(const f16x8*)(&Bs[ST][rb_ * 32 + pb_ * 8]);               \
    }                                                                         \
    _Pragma("unroll") for (int i_ = 0; i_ < 4; ++i_)                          \
    _Pragma("unroll") for (int j_ = 0; j_ < 4; ++j_)                          \
        acc[i_][j_] = __builtin_amdgcn_mfma_f32_16x16x32_f16(                 \
            af_[i_], bf_[j_], acc[i_][j_], 0, 0, 0);                          \
    } while (0)

    FIRE(0, 0); FIRE(1, 1); FIRE(2, 2);          // 12 insts in flight

    #pragma unroll 1
    for (int it = 0; it < IT_BLK - 2; ++it) {    // 0..47
        // wait own stage-it loads (oldest 4), keep 8 in flight; ensure own
        // ds_reads of stage it-1 are done before the barrier (slot-reuse safety)
        asm volatile("s_waitcnt vmcnt(8) lgkmcnt(0)" ::: "memory");
        __builtin_amdgcn_s_barrier();            // all waves: stage it ready
        if (it < IT_BLK - 3) FIRE((it + 3) & 3, it + 3);
        CONSUME(it & 3);
    }
    asm volatile("s_waitcnt vmcnt(4) lgkmcnt(0)" ::: "memory");
    __builtin_amdgcn_s_barrier();
    CONSUME((IT_BLK - 2) & 3);
    asm volatile("s_waitcnt vmcnt(0) lgkmcnt(0)" ::: "memory");
    __builtin_amdgcn_s_barrier();
    CONSUME((IT_BLK - 1) & 3);

#undef FIRE
#undef CONSUME

    // C/D layout: col = lane&15, row = quad*4 + reg. Atomic split-K reduce.
    float* Yb = Ysum + (size_t)(mt * 128) * 512 + nt * 128;
    #pragma unroll
    for (int i = 0; i < 4; ++i)
        #pragma unroll
        for (int j = 0; j < 4; ++j)
            #pragma unroll
            for (int r = 0; r < 4; ++r) {
                int row = wm + i * 16 + quad * 4 + r;
                int col = wn + j * 16 + m16;
                unsafeAtomicAdd(&Yb[(size_t)row * 512 + col], acc[i][j][r]);
            }
}

// ---------------------------------------------------------------------------
// Kernel 4: head = (relu(sum*256+b1)) -> fc2 + sigmoid -> fc3
// 8 samples/block, 128 threads -> 256 blocks per chunk.
// ---------------------------------------------------------------------------
__global__ __launch_bounds__(128) void head_fc23(const float* __restrict__ y1s,
                                                 const float* __restrict__ b1,
                                                 const float* __restrict__ w2,
                                                 const float* __restrict__ b2,
                                                 const float* __restrict__ w3,
                                                 const float* __restrict__ b3,
                                                 float* __restrict__ out, int n0)
{
    __shared__ float Ys[8 * 512];    // 16 KB
    __shared__ float Y2[8 * 128];    // 4 KB
    const int t = threadIdx.x;
    const float4* yb = (const float4*)(y1s + (size_t)blockIdx.x * 8 * 512);
    const float4* b1v = (const float4*)b1;
    for (int i = t; i < 8 * 128; i += 128) {
        float4 s = yb[i];
        float4 bv = b1v[i & 127];
        float4 y;
        y.x = fmaxf(fmaf(s.x, 256.f, bv.x), 0.f);
        y.y = fmaxf(fmaf(s.y, 256.f, bv.y), 0.f);
        y.z = fmaxf(fmaf(s.z, 256.f, bv.z), 0.f);
        y.w = fmaxf(fmaf(s.w, 256.f, bv.w), 0.f);
        ((float4*)Ys)[i] = y;
    }
    __syncthreads();

    float acc[8];
    float bk = b2[t];
    #pragma unroll
    for (int s = 0; s < 8; ++s) acc[s] = bk;
    const float4* wr = (const float4*)(w2 + (size_t)t * 512);
    for (int jc = 0; jc < 128; ++jc) {
        float4 w4 = wr[jc];
        #pragma unroll
        for (int s = 0; s < 8; ++s) {
            float4 y4 = *(const float4*)(Ys + s * 512 + jc * 4);
            acc[s] += w4.x * y4.x + w4.y * y4.y + w4.z * y4.z + w4.w * y4.w;
        }
    }
    #pragma unroll
    for (int s = 0; s < 8; ++s) Y2[s * 128 + t] = 1.0f / (1.0f + expf(-acc[s]));
    __syncthreads();

    if (t < 8) {
        float sm = b3[0];
        #pragma unroll 4
        for (int k = 0; k < 128; ++k) sm += Y2[t * 128 + k] * w3[k];
        out[n0 + blockIdx.x * 8 + t] = sm;
    }
}

// ---------------------------------------------------------------------------
extern "C" void kernel_launch(void* const* d_in, const int* in_sizes, int n_in,
                              void* d_out, int out_size, void* d_ws, size_t ws_size,
                              hipStream_t stream)
{
    const float* data = (const float*)d_in[0];
    const float* bn_g = (const float*)d_in[1];
    const float* bn_b = (const float*)d_in[2];
    const float* bn_m = (const float*)d_in[3];
    const float* bn_v = (const float*)d_in[4];
    const float* cw   = (const float*)d_in[5];
    const float* cb   = (const float*)d_in[6];
    const float* fc1w = (const float*)d_in[7];
    const float* fc1b = (const float*)d_in[8];
    const float* fc2w = (const float*)d_in[9];
    const float* fc2b = (const float*)d_in[10];
    const float* fc3w = (const float*)d_in[11];
    const float* fc3b = (const float*)d_in[12];
    float* out = (float*)d_out;

    // workspace layout (total ~225.6 MB, known-safe)
    const size_t A16_BYTES = (size_t)CHUNK * K_FC1 * 2;       // 176,947,200
    const size_t W16_BYTES = (size_t)512 * K_FC1 * 2;         //  44,236,800
    const size_t Y1_BYTES  = (size_t)CHUNK * 512 * 4;         //   4,194,304
    if (ws_size < A16_BYTES + W16_BYTES + Y1_BYTES) return;

    char* ws = (char*)d_ws;
    f16*   A16 = (f16*)ws;
    f16*   W16 = (f16*)(ws + A16_BYTES);
    float* y1s = (float*)(ws + A16_BYTES + W16_BYTES);

    retile_w<<<4 * IT_TOT, 256, 0, stream>>>(fc1w, W16);

    for (int c = 0; c < 2; ++c) {
        int n0 = c * CHUNK;
        hipMemsetAsync(y1s, 0, Y1_BYTES, stream);
        stage_a<<<CHUNK, 256, 0, stream>>>(data, bn_g, bn_b, bn_m, bn_v, cw, cb, A16, n0);
        gemm_fc1<<<8 * 216, 256, 0, stream>>>(A16, W16, y1s);
        head_fc23<<<CHUNK / 8, 128, 0, stream>>>(y1s, fc1b, fc2w, fc2b, fc3w, fc3b, out, n0);
    }
}

// Round 8
// 726.514 us; speedup vs baseline: 1.1729x; 1.0223x over previous
//
#include <hip/hip_runtime.h>
#include <cstdint>
#include <cstddef>

// ---------------------------------------------------------------------------
// AlphaNet: features -> BN -> conv(1x3,16) -> relu -> fc1(43200->512) -> relu
//          -> fc2(512->128) -> sigmoid -> fc3(128->1)
// fc1 = f16 MFMA GEMM (A scaled 2^-8), split-K=27, atomic fp32 reduce.
// R8: R7 (256x256 tiles, 128KB 4-deep LDS ring, manual vmcnt, XCD-pin)
//     with the grid-size bug fixed: 432 blocks (mt 8 x nt 2 x sk 27).
// ---------------------------------------------------------------------------

typedef _Float16 f16;
typedef f16 f16x8 __attribute__((ext_vector_type(8)));
typedef float f32x4 __attribute__((ext_vector_type(4)));

#define CHUNK    2048              // samples per pipeline pass (2 passes)
#define K_FC1    43200             // 16*270*10
#define IT_TOT   1350              // K_FC1 / 32
#define SPLITK   27
#define IT_BLK   50                // 1350 / 27
#define MT_CHUNK 8                 // 2048 / 256 M-tiles
#define TILE_E   8192              // 256 rows * 32 f16 per (tile,it) block (16KB)

__device__ __forceinline__ float fillv(float x) { return isfinite(x) ? x : 0.0f; }

// ---------------------------------------------------------------------------
// Kernel 1: fc1_w fp32 -> f16, retiled to [nt(2)][it(1350)][256][32] with
// 16B-unit swizzle: unit u of row r stored at position (u + (r>>1)) & 3.
// One block per (nt,it) = 2700 blocks, 1024 units each.
// ---------------------------------------------------------------------------
__global__ __launch_bounds__(256) void retile_w(const float* __restrict__ w,
                                                f16* __restrict__ Wt) {
    const int bid = blockIdx.x;               // nt*1350 + it
    const int nt = bid / IT_TOT, it = bid % IT_TOT;
    const int t = threadIdx.x;
    f16* dst = Wt + (size_t)bid * TILE_E;
    #pragma unroll
    for (int j = 0; j < 4; ++j) {
        int t2 = t + 256 * j;                 // 0..1023 16B units
        int r = t2 >> 2, u = t2 & 3;          // row (0..255), k-octet
        const float* s = w + (size_t)(nt * 256 + r) * K_FC1 + it * 32 + u * 8;
        float4 a = *(const float4*)s;
        float4 b = *(const float4*)(s + 4);
        f16x8 o = { (f16)a.x, (f16)a.y, (f16)a.z, (f16)a.w,
                    (f16)b.x, (f16)b.y, (f16)b.z, (f16)b.w };
        int p = (u + (r >> 1)) & 3;
        *(f16x8*)(dst + (size_t)r * 32 + p * 8) = o;
    }
}

// ---------------------------------------------------------------------------
// Kernel 2: per-sample features + BN + conv + relu -> A16 tiled+swizzled
// (scaled 2^-8). A layout: [mt(8)][it(1350)][256][32] f16, same swizzle.
// One block per sample; per (it) the sample writes one contiguous 64B run.
// ---------------------------------------------------------------------------
__global__ __launch_bounds__(256) void stage_a(
    const float* __restrict__ data, const float* __restrict__ bn_g,
    const float* __restrict__ bn_b, const float* __restrict__ bn_m,
    const float* __restrict__ bn_v, const float* __restrict__ conv_w,
    const float* __restrict__ conv_b, f16* __restrict__ A16, int n0)
{
    __shared__ float raw[1800];        // raw window data, becomes spread
    __shared__ float feat[270 * 12];
    __shared__ float cw[48];
    __shared__ float cb[16];
    __shared__ int   pi[105], pj[105];

    const int t = threadIdx.x;
    const int n = n0 + blockIdx.x;
    const float4* src4 = (const float4*)(data + (size_t)n * 1800);
    for (int i = t; i < 450; i += 256) ((float4*)raw)[i] = src4[i];
    if (t < 48)  cw[t] = conv_w[t];
    if (t < 16)  cb[t] = conv_b[t];
    if (t < 105) {                               // triu_indices(15, k=1) order
        int i = 0, rem = t;
        while (rem >= 14 - i) { rem -= 14 - i; ++i; }
        pi[t] = i; pj[t] = i + 1 + rem;
    }
    __syncthreads();

    // per-(f,w) stats; overwrite raw with spread
    if (t < 180) {
        int f = t / 12, w = t % 12;
        int base = f * 120 + w * 10;
        float x[10];
        #pragma unroll
        for (int s = 0; s < 10; ++s) x[s] = raw[base + s];
        float sum = 0.f;
        #pragma unroll
        for (int s = 0; s < 10; ++s) sum += x[s];
        float mean = sum * 0.1f;
        float ret = x[9] / x[0] - 1.0f;
        float dl = 0.f;
        #pragma unroll
        for (int s = 0; s < 10; ++s) dl += x[s] * ((float)(s + 1) * (1.0f / 55.0f));
        float var = 0.f;
        #pragma unroll
        for (int s = 0; s < 10; ++s) { float d = x[s] - mean; raw[base + s] = d; var += d * d; }
        var *= (1.0f / 9.0f);                    // unbiased
        float sd = sqrtf(var);
        feat[(210 + f) * 12 + w] = fillv(sd);
        feat[(225 + f) * 12 + w] = fillv(mean / sd);
        feat[(240 + f) * 12 + w] = fillv(ret);
        feat[(255 + f) * 12 + w] = fillv(dl);
    }
    __syncthreads();

    // pairwise cov / corr
    for (int q = t; q < 1260; q += 256) {
        int p = q / 12, w = q % 12;
        int i = pi[p], j = pj[p];
        int bi = i * 120 + w * 10, bj = j * 120 + w * 10;
        float cv = 0.f;
        #pragma unroll
        for (int s = 0; s < 10; ++s) cv += raw[bi + s] * raw[bj + s];
        cv *= (1.0f / 9.0f);
        float si = feat[(210 + i) * 12 + w], sj = feat[(210 + j) * 12 + w];
        feat[p * 12 + w]         = fillv(cv / (si * sj) * 0.9f);  // *(S-1)/S
        feat[(105 + p) * 12 + w] = fillv(cv);
    }
    __syncthreads();

    // BatchNorm (eval, C=1 scalar)
    float a  = bn_g[0] * rsqrtf(bn_v[0] + 1e-5f);
    float bb = bn_b[0] - bn_m[0] * a;
    for (int i = t; i < 3240; i += 256) feat[i] = feat[i] * a + bb;
    __syncthreads();

    // conv(1x3) + bias + relu -> scale 2^-8 -> clamp -> f16 -> tiled+swizzled
    const int s_idx = blockIdx.x;                // sample within chunk
    const int mt = s_idx >> 8, r = s_idx & 255;
    const int rsw = (r >> 1) & 3;
    f16* base = A16 + (size_t)mt * IT_TOT * TILE_E + (size_t)r * 32;
    for (int v = t; v < K_FC1 / 8; v += 256) {   // 5400 16B units
        int idx0 = v * 8;
        f16x8 ov;
        #pragma unroll
        for (int e = 0; e < 8; ++e) {
            int idx = idx0 + e;
            int oc = idx / 2700;
            int rem = idx - oc * 2700;
            int h = rem / 10;
            int wo = rem - h * 10;
            const float* fr = feat + h * 12 + wo;
            float y = cb[oc] + cw[oc * 3] * fr[0] + cw[oc * 3 + 1] * fr[1] + cw[oc * 3 + 2] * fr[2];
            y = y > 0.f ? y : 0.f;
            y *= 0.00390625f;                    // 2^-8 (exact)
            y = y < 65000.f ? y : 65000.f;       // fp16-overflow backstop
            ov[e] = (f16)y;
        }
        int it = v >> 2, u = v & 3;
        int p = (u + rsw) & 3;
        *(f16x8*)(base + (size_t)it * TILE_E + p * 8) = ov;
    }
}

// ---------------------------------------------------------------------------
// Kernel 3: fc1 GEMM  Ysum[CHUNK,512] (+)= A * W^T (f16 MFMA)
// 256x256 tile, 16 waves (1024 thr), each wave 64x64. BK=32, split-K=27
// -> 432 blocks. 4-deep LDS ring (128 KB), raw s_barrier + manual vmcnt.
// XCD pin: mt = bid&7 -> per XCD the (nt,sk) slots share A-slices
// (L2-deduped); A read once from LLC total.
// ---------------------------------------------------------------------------
__global__ __launch_bounds__(1024, 1) void gemm_fc1(const f16* __restrict__ A,
                                                    const f16* __restrict__ W,
                                                    float* __restrict__ Ysum)
{
    __shared__ f16 As[4][TILE_E];   // 4 x 16KB
    __shared__ f16 Bs[4][TILE_E];   // 4 x 16KB  (total 128 KB)

    const int bid = blockIdx.x;                   // 432 blocks
    const int mt = bid & 7;                       // XCD-pinned M-tile
    const int slot = bid >> 3;                    // 0..53
    const int nt = slot & 1;
    const int sk = slot >> 1;                     // 0..26

    const int tid = threadIdx.x;
    const int wave = tid >> 6, lane = tid & 63;
    const int quad = lane >> 4, m16 = lane & 15;
    const int wm = (wave & 3) << 6, wn = (wave >> 2) << 6;

    const f16* Ab = A + (size_t)(mt * IT_TOT + sk * IT_BLK) * TILE_E;
    const f16* Bb = W + (size_t)(nt * IT_TOT + sk * IT_BLK) * TILE_E;

    f32x4 acc[4][4] = {};

    // fire one ring stage: each wave stages 1KB of A + 1KB of B (2 insts)
#define FIRE(ST, IT) do {                                                     \
    const f16* At_ = Ab + (size_t)(IT) * TILE_E;                              \
    const f16* Bt_ = Bb + (size_t)(IT) * TILE_E;                              \
    __builtin_amdgcn_global_load_lds(                                         \
        (const __attribute__((address_space(1))) void*)(At_ + wave * 512 + lane * 8), \
        (__attribute__((address_space(3))) void*)(&As[ST][wave * 512]),       \
        16, 0, 0);                                                            \
    __builtin_amdgcn_global_load_lds(                                         \
        (const __attribute__((address_space(1))) void*)(Bt_ + wave * 512 + lane * 8), \
        (__attribute__((address_space(3))) void*)(&Bs[ST][wave * 512]),       \
        16, 0, 0);                                                            \
    } while (0)

#define CONSUME(ST) do {                                                      \
    f16x8 af_[4], bf_[4];                                                     \
    _Pragma("unroll") for (int i_ = 0; i_ < 4; ++i_) {                        \
        int ra_ = wm + i_ * 16 + m16;                                         \
        int pa_ = (quad + (ra_ >> 1)) & 3;                                    \
        af_[i_] = *(const f16x8*)(&As[ST][ra_ * 32 + pa_ * 8]);               \
        int rb_ = wn + i_ * 16 + m16;                                         \
        int pb_ = (quad + (rb_ >> 1)) & 3;                                    \
        bf_[i_] = *(const f16x8*)(&Bs[ST][rb_ * 32 + pb_ * 8]);               \
    }                                                                         \
    _Pragma("unroll") for (int i_ = 0; i_ < 4; ++i_)                          \
    _Pragma("unroll") for (int j_ = 0; j_ < 4; ++j_)                          \
        acc[i_][j_] = __builtin_amdgcn_mfma_f32_16x16x32_f16(                 \
            af_[i_], bf_[j_], acc[i_][j_], 0, 0, 0);                          \
    } while (0)

    FIRE(0, 0); FIRE(1, 1); FIRE(2, 2);          // 6 insts/wave in flight

    #pragma unroll 1
    for (int it = 0; it < IT_BLK - 2; ++it) {    // 0..47
        // wait own stage-it loads (oldest 2), keep 4 in flight; lgkmcnt(0)
        // guards slot reuse (own ds_reads of stage it-1 done before barrier)
        asm volatile("s_waitcnt vmcnt(4) lgkmcnt(0)" ::: "memory");
        __builtin_amdgcn_s_barrier();            // all waves: stage it ready
        if (it < IT_BLK - 3) FIRE((it + 3) & 3, it + 3);
        CONSUME(it & 3);
    }
    asm volatile("s_waitcnt vmcnt(2) lgkmcnt(0)" ::: "memory");
    __builtin_amdgcn_s_barrier();
    CONSUME((IT_BLK - 2) & 3);
    asm volatile("s_waitcnt vmcnt(0) lgkmcnt(0)" ::: "memory");
    __builtin_amdgcn_s_barrier();
    CONSUME((IT_BLK - 1) & 3);

#undef FIRE
#undef CONSUME

    // C/D layout: col = lane&15, row = quad*4 + reg. Atomic split-K reduce.
    float* Yb = Ysum + (size_t)(mt * 256) * 512 + nt * 256;
    #pragma unroll
    for (int i = 0; i < 4; ++i)
        #pragma unroll
        for (int j = 0; j < 4; ++j)
            #pragma unroll
            for (int r = 0; r < 4; ++r) {
                int row = wm + i * 16 + quad * 4 + r;
                int col = wn + j * 16 + m16;
                unsafeAtomicAdd(&Yb[(size_t)row * 512 + col], acc[i][j][r]);
            }
}

// ---------------------------------------------------------------------------
// Kernel 4: head = (relu(sum*256+b1)) -> fc2 + sigmoid -> fc3
// 8 samples/block, 128 threads -> 256 blocks per chunk.
// ---------------------------------------------------------------------------
__global__ __launch_bounds__(128) void head_fc23(const float* __restrict__ y1s,
                                                 const float* __restrict__ b1,
                                                 const float* __restrict__ w2,
                                                 const float* __restrict__ b2,
                                                 const float* __restrict__ w3,
                                                 const float* __restrict__ b3,
                                                 float* __restrict__ out, int n0)
{
    __shared__ float Ys[8 * 512];    // 16 KB
    __shared__ float Y2[8 * 128];    // 4 KB
    const int t = threadIdx.x;
    const float4* yb = (const float4*)(y1s + (size_t)blockIdx.x * 8 * 512);
    const float4* b1v = (const float4*)b1;
    for (int i = t; i < 8 * 128; i += 128) {
        float4 s = yb[i];
        float4 bv = b1v[i & 127];
        float4 y;
        y.x = fmaxf(fmaf(s.x, 256.f, bv.x), 0.f);
        y.y = fmaxf(fmaf(s.y, 256.f, bv.y), 0.f);
        y.z = fmaxf(fmaf(s.z, 256.f, bv.z), 0.f);
        y.w = fmaxf(fmaf(s.w, 256.f, bv.w), 0.f);
        ((float4*)Ys)[i] = y;
    }
    __syncthreads();

    float acc[8];
    float bk = b2[t];
    #pragma unroll
    for (int s = 0; s < 8; ++s) acc[s] = bk;
    const float4* wr = (const float4*)(w2 + (size_t)t * 512);
    for (int jc = 0; jc < 128; ++jc) {
        float4 w4 = wr[jc];
        #pragma unroll
        for (int s = 0; s < 8; ++s) {
            float4 y4 = *(const float4*)(Ys + s * 512 + jc * 4);
            acc[s] += w4.x * y4.x + w4.y * y4.y + w4.z * y4.z + w4.w * y4.w;
        }
    }
    #pragma unroll
    for (int s = 0; s < 8; ++s) Y2[s * 128 + t] = 1.0f / (1.0f + expf(-acc[s]));
    __syncthreads();

    if (t < 8) {
        float sm = b3[0];
        #pragma unroll 4
        for (int k = 0; k < 128; ++k) sm += Y2[t * 128 + k] * w3[k];
        out[n0 + blockIdx.x * 8 + t] = sm;
    }
}

// ---------------------------------------------------------------------------
extern "C" void kernel_launch(void* const* d_in, const int* in_sizes, int n_in,
                              void* d_out, int out_size, void* d_ws, size_t ws_size,
                              hipStream_t stream)
{
    const float* data = (const float*)d_in[0];
    const float* bn_g = (const float*)d_in[1];
    const float* bn_b = (const float*)d_in[2];
    const float* bn_m = (const float*)d_in[3];
    const float* bn_v = (const float*)d_in[4];
    const float* cw   = (const float*)d_in[5];
    const float* cb   = (const float*)d_in[6];
    const float* fc1w = (const float*)d_in[7];
    const float* fc1b = (const float*)d_in[8];
    const float* fc2w = (const float*)d_in[9];
    const float* fc2b = (const float*)d_in[10];
    const float* fc3w = (const float*)d_in[11];
    const float* fc3b = (const float*)d_in[12];
    float* out = (float*)d_out;

    // workspace layout (total ~225.6 MB, known-safe)
    const size_t A16_BYTES = (size_t)CHUNK * K_FC1 * 2;       // 176,947,200
    const size_t W16_BYTES = (size_t)512 * K_FC1 * 2;         //  44,236,800
    const size_t Y1_BYTES  = (size_t)CHUNK * 512 * 4;         //   4,194,304
    if (ws_size < A16_BYTES + W16_BYTES + Y1_BYTES) return;

    char* ws = (char*)d_ws;
    f16*   A16 = (f16*)ws;
    f16*   W16 = (f16*)(ws + A16_BYTES);
    float* y1s = (float*)(ws + A16_BYTES + W16_BYTES);

    retile_w<<<2 * IT_TOT, 256, 0, stream>>>(fc1w, W16);

    for (int c = 0; c < 2; ++c) {
        int n0 = c * CHUNK;
        hipMemsetAsync(y1s, 0, Y1_BYTES, stream);
        stage_a<<<CHUNK, 256, 0, stream>>>(data, bn_g, bn_b, bn_m, bn_v, cw, cb, A16, n0);
        gemm_fc1<<<MT_CHUNK * 2 * SPLITK, 1024, 0, stream>>>(A16, W16, y1s);  // 432 blocks
        head_fc23<<<CHUNK / 8, 128, 0, stream>>>(y1s, fc1b, fc2w, fc2b, fc3w, fc3b, out, n0);
    }
}

// Round 9
// 711.234 us; speedup vs baseline: 1.1981x; 1.0215x over previous
//
#include <hip/hip_runtime.h>
#include <cstdint>
#include <cstddef>

// ---------------------------------------------------------------------------
// AlphaNet: features -> BN -> conv(1x3,16) -> relu -> fc1(43200->512) -> relu
//          -> fc2(512->128) -> sigmoid -> fc3(128->1)
// fc1 = f16 MFMA GEMM (A scaled 2^-8), atomic fp32 split-K reduce.
// R9: 256x256 tiles (halved staged traffic, R8-verified) + depth-2 LDS ring
//     at 64 KB -> 2 blocks/CU co-tenancy (R3-verified 6.9 TB/s staging).
//     2-barrier/iter protocol with FIRE-before-wait: vmcnt never drains to 0
//     in steady state. Grid 512 = 8 mt x 2 nt x 32 sk -> exactly 2/CU, no
//     dispatch tail. Uneven K split (6x43 + 26x42 BK=32 stages).
// ---------------------------------------------------------------------------

typedef _Float16 f16;
typedef f16 f16x8 __attribute__((ext_vector_type(8)));
typedef float f32x4 __attribute__((ext_vector_type(4)));

#define CHUNK    2048              // samples per pipeline pass (2 passes)
#define K_FC1    43200             // 16*270*10
#define IT_TOT   1350              // K_FC1 / 32
#define MT_CHUNK 8                 // 2048 / 256 M-tiles
#define TILE_E   8192              // 256 rows * 32 f16 per (tile,it) block (16KB)

__device__ __forceinline__ float fillv(float x) { return isfinite(x) ? x : 0.0f; }

// ---------------------------------------------------------------------------
// Kernel 1: fc1_w fp32 -> f16, retiled to [nt(2)][it(1350)][256][32] with
// 16B-unit swizzle: unit u of row r stored at position (u + (r>>1)) & 3.
// One block per (nt,it) = 2700 blocks, 1024 units each.
// ---------------------------------------------------------------------------
__global__ __launch_bounds__(256) void retile_w(const float* __restrict__ w,
                                                f16* __restrict__ Wt) {
    const int bid = blockIdx.x;               // nt*1350 + it
    const int nt = bid / IT_TOT, it = bid % IT_TOT;
    const int t = threadIdx.x;
    f16* dst = Wt + (size_t)bid * TILE_E;
    #pragma unroll
    for (int j = 0; j < 4; ++j) {
        int t2 = t + 256 * j;                 // 0..1023 16B units
        int r = t2 >> 2, u = t2 & 3;          // row (0..255), k-octet
        const float* s = w + (size_t)(nt * 256 + r) * K_FC1 + it * 32 + u * 8;
        float4 a = *(const float4*)s;
        float4 b = *(const float4*)(s + 4);
        f16x8 o = { (f16)a.x, (f16)a.y, (f16)a.z, (f16)a.w,
                    (f16)b.x, (f16)b.y, (f16)b.z, (f16)b.w };
        int p = (u + (r >> 1)) & 3;
        *(f16x8*)(dst + (size_t)r * 32 + p * 8) = o;
    }
}

// ---------------------------------------------------------------------------
// Kernel 2: per-sample features + BN + conv + relu -> A16 tiled+swizzled
// (scaled 2^-8). A layout: [mt(8)][it(1350)][256][32] f16, same swizzle.
// One block per sample; per (it) the sample writes one contiguous 64B run.
// ---------------------------------------------------------------------------
__global__ __launch_bounds__(256) void stage_a(
    const float* __restrict__ data, const float* __restrict__ bn_g,
    const float* __restrict__ bn_b, const float* __restrict__ bn_m,
    const float* __restrict__ bn_v, const float* __restrict__ conv_w,
    const float* __restrict__ conv_b, f16* __restrict__ A16, int n0)
{
    __shared__ float raw[1800];        // raw window data, becomes spread
    __shared__ float feat[270 * 12];
    __shared__ float cw[48];
    __shared__ float cb[16];
    __shared__ int   pi[105], pj[105];

    const int t = threadIdx.x;
    const int n = n0 + blockIdx.x;
    const float4* src4 = (const float4*)(data + (size_t)n * 1800);
    for (int i = t; i < 450; i += 256) ((float4*)raw)[i] = src4[i];
    if (t < 48)  cw[t] = conv_w[t];
    if (t < 16)  cb[t] = conv_b[t];
    if (t < 105) {                               // triu_indices(15, k=1) order
        int i = 0, rem = t;
        while (rem >= 14 - i) { rem -= 14 - i; ++i; }
        pi[t] = i; pj[t] = i + 1 + rem;
    }
    __syncthreads();

    // per-(f,w) stats; overwrite raw with spread
    if (t < 180) {
        int f = t / 12, w = t % 12;
        int base = f * 120 + w * 10;
        float x[10];
        #pragma unroll
        for (int s = 0; s < 10; ++s) x[s] = raw[base + s];
        float sum = 0.f;
        #pragma unroll
        for (int s = 0; s < 10; ++s) sum += x[s];
        float mean = sum * 0.1f;
        float ret = x[9] / x[0] - 1.0f;
        float dl = 0.f;
        #pragma unroll
        for (int s = 0; s < 10; ++s) dl += x[s] * ((float)(s + 1) * (1.0f / 55.0f));
        float var = 0.f;
        #pragma unroll
        for (int s = 0; s < 10; ++s) { float d = x[s] - mean; raw[base + s] = d; var += d * d; }
        var *= (1.0f / 9.0f);                    // unbiased
        float sd = sqrtf(var);
        feat[(210 + f) * 12 + w] = fillv(sd);
        feat[(225 + f) * 12 + w] = fillv(mean / sd);
        feat[(240 + f) * 12 + w] = fillv(ret);
        feat[(255 + f) * 12 + w] = fillv(dl);
    }
    __syncthreads();

    // pairwise cov / corr
    for (int q = t; q < 1260; q += 256) {
        int p = q / 12, w = q % 12;
        int i = pi[p], j = pj[p];
        int bi = i * 120 + w * 10, bj = j * 120 + w * 10;
        float cv = 0.f;
        #pragma unroll
        for (int s = 0; s < 10; ++s) cv += raw[bi + s] * raw[bj + s];
        cv *= (1.0f / 9.0f);
        float si = feat[(210 + i) * 12 + w], sj = feat[(210 + j) * 12 + w];
        feat[p * 12 + w]         = fillv(cv / (si * sj) * 0.9f);  // *(S-1)/S
        feat[(105 + p) * 12 + w] = fillv(cv);
    }
    __syncthreads();

    // BatchNorm (eval, C=1 scalar)
    float a  = bn_g[0] * rsqrtf(bn_v[0] + 1e-5f);
    float bb = bn_b[0] - bn_m[0] * a;
    for (int i = t; i < 3240; i += 256) feat[i] = feat[i] * a + bb;
    __syncthreads();

    // conv(1x3) + bias + relu -> scale 2^-8 -> clamp -> f16 -> tiled+swizzled
    const int s_idx = blockIdx.x;                // sample within chunk
    const int mt = s_idx >> 8, r = s_idx & 255;
    const int rsw = (r >> 1) & 3;
    f16* base = A16 + (size_t)mt * IT_TOT * TILE_E + (size_t)r * 32;
    for (int v = t; v < K_FC1 / 8; v += 256) {   // 5400 16B units
        int idx0 = v * 8;
        f16x8 ov;
        #pragma unroll
        for (int e = 0; e < 8; ++e) {
            int idx = idx0 + e;
            int oc = idx / 2700;
            int rem = idx - oc * 2700;
            int h = rem / 10;
            int wo = rem - h * 10;
            const float* fr = feat + h * 12 + wo;
            float y = cb[oc] + cw[oc * 3] * fr[0] + cw[oc * 3 + 1] * fr[1] + cw[oc * 3 + 2] * fr[2];
            y = y > 0.f ? y : 0.f;
            y *= 0.00390625f;                    // 2^-8 (exact)
            y = y < 65000.f ? y : 65000.f;       // fp16-overflow backstop
            ov[e] = (f16)y;
        }
        int it = v >> 2, u = v & 3;
        int p = (u + rsw) & 3;
        *(f16x8*)(base + (size_t)it * TILE_E + p * 8) = ov;
    }
}

// ---------------------------------------------------------------------------
// Kernel 3: fc1 GEMM  Ysum[CHUNK,512] (+)= A * W^T (f16 MFMA)
// 256x256 tile, 16 waves (1024 thr), each wave 64x64. BK=32, depth-2 LDS
// ring (64 KB -> 2 blocks/CU). 512 blocks = mt8 x nt2 x sk32, uneven K split.
// 2 barriers/iter; FIRE precedes waits so vmcnt >= 2 in steady state.
// XCD pin: mt = bid&7 -> A-slices L2-deduped within an XCD.
// ---------------------------------------------------------------------------
__global__ __launch_bounds__(1024, 1) void gemm_fc1(const f16* __restrict__ A,
                                                    const f16* __restrict__ W,
                                                    float* __restrict__ Ysum)
{
    __shared__ f16 As[2][TILE_E];   // 2 x 16KB
    __shared__ f16 Bs[2][TILE_E];   // 2 x 16KB  (total 64 KB)

    const int bid = blockIdx.x;                   // 512 blocks
    const int mt = bid & 7;                       // XCD-pinned M-tile
    const int slot = bid >> 3;                    // 0..63
    const int nt = slot & 1;
    const int sk = slot >> 1;                     // 0..31
    const int it0 = sk * 42 + (sk < 6 ? sk : 6);  // uneven split: 6x43+26x42
    const int cnt = 42 + (sk < 6 ? 1 : 0);

    const int tid = threadIdx.x;
    const int wave = tid >> 6, lane = tid & 63;
    const int quad = lane >> 4, m16 = lane & 15;
    const int wm = (wave & 3) << 6, wn = (wave >> 2) << 6;

    const f16* Ab = A + (size_t)(mt * IT_TOT + it0) * TILE_E;
    const f16* Bb = W + (size_t)(nt * IT_TOT + it0) * TILE_E;

    f32x4 acc[4][4] = {};

    // fire one ring stage: each wave stages 1KB of A + 1KB of B (2 insts)
#define FIRE(ST, IT) do {                                                     \
    const f16* At_ = Ab + (size_t)(IT) * TILE_E;                              \
    const f16* Bt_ = Bb + (size_t)(IT) * TILE_E;                              \
    __builtin_amdgcn_global_load_lds(                                         \
        (const __attribute__((address_space(1))) void*)(At_ + wave * 512 + lane * 8), \
        (__attribute__((address_space(3))) void*)(&As[ST][wave * 512]),       \
        16, 0, 0);                                                            \
    __builtin_amdgcn_global_load_lds(                                         \
        (const __attribute__((address_space(1))) void*)(Bt_ + wave * 512 + lane * 8), \
        (__attribute__((address_space(3))) void*)(&Bs[ST][wave * 512]),       \
        16, 0, 0);                                                            \
    } while (0)

#define CONSUME(ST) do {                                                      \
    f16x8 af_[4], bf_[4];                                                     \
    _Pragma("unroll") for (int i_ = 0; i_ < 4; ++i_) {                        \
        int ra_ = wm + i_ * 16 + m16;                                         \
        int pa_ = (quad + (ra_ >> 1)) & 3;                                    \
        af_[i_] = *(const f16x8*)(&As[ST][ra_ * 32 + pa_ * 8]);               \
        int rb_ = wn + i_ * 16 + m16;                                         \
        int pb_ = (quad + (rb_ >> 1)) & 3;                                    \
        bf_[i_] = *(const f16x8*)(&Bs[ST][rb_ * 32 + pb_ * 8]);               \
    }                                                                         \
    _Pragma("unroll") for (int i_ = 0; i_ < 4; ++i_)                          \
    _Pragma("unroll") for (int j_ = 0; j_ < 4; ++j_)                          \
        acc[i_][j_] = __builtin_amdgcn_mfma_f32_16x16x32_f16(                 \
            af_[i_], bf_[j_], acc[i_][j_], 0, 0, 0);                          \
    } while (0)

    FIRE(0, 0);                                  // 2 insts/wave in flight

    #pragma unroll 1
    for (int i = 0; i < cnt - 1; ++i) {
        FIRE((i + 1) & 1, i + 1);                // now 4 in flight
        // wait own stage-i loads (oldest 2) landed; keep stage-(i+1) flying
        asm volatile("s_waitcnt vmcnt(2) lgkmcnt(0)" ::: "memory");
        __builtin_amdgcn_s_barrier();            // stage i ready for all waves
        CONSUME(i & 1);
        __builtin_amdgcn_s_barrier();            // all done reading slot i&1
        // next iter's FIRE overwrites slot i&1 -- safe after this barrier
    }
    asm volatile("s_waitcnt vmcnt(0) lgkmcnt(0)" ::: "memory");
    __builtin_amdgcn_s_barrier();
    CONSUME((cnt - 1) & 1);

#undef FIRE
#undef CONSUME

    // C/D layout: col = lane&15, row = quad*4 + reg. Atomic split-K reduce.
    float* Yb = Ysum + (size_t)(mt * 256) * 512 + nt * 256;
    #pragma unroll
    for (int i = 0; i < 4; ++i)
        #pragma unroll
        for (int j = 0; j < 4; ++j)
            #pragma unroll
            for (int r = 0; r < 4; ++r) {
                int row = wm + i * 16 + quad * 4 + r;
                int col = wn + j * 16 + m16;
                unsafeAtomicAdd(&Yb[(size_t)row * 512 + col], acc[i][j][r]);
            }
}

// ---------------------------------------------------------------------------
// Kernel 4: head = (relu(sum*256+b1)) -> fc2 + sigmoid -> fc3
// 8 samples/block, 128 threads -> 256 blocks per chunk.
// ---------------------------------------------------------------------------
__global__ __launch_bounds__(128) void head_fc23(const float* __restrict__ y1s,
                                                 const float* __restrict__ b1,
                                                 const float* __restrict__ w2,
                                                 const float* __restrict__ b2,
                                                 const float* __restrict__ w3,
                                                 const float* __restrict__ b3,
                                                 float* __restrict__ out, int n0)
{
    __shared__ float Ys[8 * 512];    // 16 KB
    __shared__ float Y2[8 * 128];    // 4 KB
    const int t = threadIdx.x;
    const float4* yb = (const float4*)(y1s + (size_t)blockIdx.x * 8 * 512);
    const float4* b1v = (const float4*)b1;
    for (int i = t; i < 8 * 128; i += 128) {
        float4 s = yb[i];
        float4 bv = b1v[i & 127];
        float4 y;
        y.x = fmaxf(fmaf(s.x, 256.f, bv.x), 0.f);
        y.y = fmaxf(fmaf(s.y, 256.f, bv.y), 0.f);
        y.z = fmaxf(fmaf(s.z, 256.f, bv.z), 0.f);
        y.w = fmaxf(fmaf(s.w, 256.f, bv.w), 0.f);
        ((float4*)Ys)[i] = y;
    }
    __syncthreads();

    float acc[8];
    float bk = b2[t];
    #pragma unroll
    for (int s = 0; s < 8; ++s) acc[s] = bk;
    const float4* wr = (const float4*)(w2 + (size_t)t * 512);
    for (int jc = 0; jc < 128; ++jc) {
        float4 w4 = wr[jc];
        #pragma unroll
        for (int s = 0; s < 8; ++s) {
            float4 y4 = *(const float4*)(Ys + s * 512 + jc * 4);
            acc[s] += w4.x * y4.x + w4.y * y4.y + w4.z * y4.z + w4.w * y4.w;
        }
    }
    #pragma unroll
    for (int s = 0; s < 8; ++s) Y2[s * 128 + t] = 1.0f / (1.0f + expf(-acc[s]));
    __syncthreads();

    if (t < 8) {
        float sm = b3[0];
        #pragma unroll 4
        for (int k = 0; k < 128; ++k) sm += Y2[t * 128 + k] * w3[k];
        out[n0 + blockIdx.x * 8 + t] = sm;
    }
}

// ---------------------------------------------------------------------------
extern "C" void kernel_launch(void* const* d_in, const int* in_sizes, int n_in,
                              void* d_out, int out_size, void* d_ws, size_t ws_size,
                              hipStream_t stream)
{
    const float* data = (const float*)d_in[0];
    const float* bn_g = (const float*)d_in[1];
    const float* bn_b = (const float*)d_in[2];
    const float* bn_m = (const float*)d_in[3];
    const float* bn_v = (const float*)d_in[4];
    const float* cw   = (const float*)d_in[5];
    const float* cb   = (const float*)d_in[6];
    const float* fc1w = (const float*)d_in[7];
    const float* fc1b = (const float*)d_in[8];
    const float* fc2w = (const float*)d_in[9];
    const float* fc2b = (const float*)d_in[10];
    const float* fc3w = (const float*)d_in[11];
    const float* fc3b = (const float*)d_in[12];
    float* out = (float*)d_out;

    // workspace layout (total ~225.6 MB, known-safe)
    const size_t A16_BYTES = (size_t)CHUNK * K_FC1 * 2;       // 176,947,200
    const size_t W16_BYTES = (size_t)512 * K_FC1 * 2;         //  44,236,800
    const size_t Y1_BYTES  = (size_t)CHUNK * 512 * 4;         //   4,194,304
    if (ws_size < A16_BYTES + W16_BYTES + Y1_BYTES) return;

    char* ws = (char*)d_ws;
    f16*   A16 = (f16*)ws;
    f16*   W16 = (f16*)(ws + A16_BYTES);
    float* y1s = (float*)(ws + A16_BYTES + W16_BYTES);

    retile_w<<<2 * IT_TOT, 256, 0, stream>>>(fc1w, W16);

    for (int c = 0; c < 2; ++c) {
        int n0 = c * CHUNK;
        hipMemsetAsync(y1s, 0, Y1_BYTES, stream);
        stage_a<<<CHUNK, 256, 0, stream>>>(data, bn_g, bn_b, bn_m, bn_v, cw, cb, A16, n0);
        gemm_fc1<<<512, 1024, 0, stream>>>(A16, W16, y1s);
        head_fc23<<<CHUNK / 8, 128, 0, stream>>>(y1s, fc1b, fc2w, fc2b, fc3w, fc3b, out, n0);
    }
}